// Round 2
// baseline (488.344 us; speedup 1.0000x reference)
//
#include <hip/hip_runtime.h>

typedef unsigned short u16;
typedef unsigned int u32;
typedef __attribute__((ext_vector_type(8))) short bf16x8;
typedef __attribute__((ext_vector_type(4))) float f32x4;

#define MX_ 4096      // B*N1 rows of x-stream
#define NT_ 1152      // N1+N2 tokens
#define C_  1152
#define DP_ 96        // padded head dim for QK contraction
#define D_  72
#define H_  16

static __device__ __forceinline__ float b2f(u16 u){ union{u32 i; float f;} x; x.i=((u32)u)<<16; return x.f; }
static __device__ __forceinline__ u16 f2b(float f){ u32 i=__float_as_uint(f); return (u16)((i + 0x7FFFu + ((i>>16)&1u))>>16); }

static __device__ __forceinline__ void gl_lds16(const u16* g, u16* l){
  __builtin_amdgcn_global_load_lds((const __attribute__((address_space(1))) void*)g,
                                   (__attribute__((address_space(3))) void*)l, 16, 0, 0);
}

// ---------------- transpose (K,N) fp32 -> (N,K) bf16 for all 8 weight matrices ----------------
struct TrArgs {
  const float* src[8]; u16* dst[8]; int K[8]; int N[8]; int start[9];
};

__global__ __launch_bounds__(256) void transpose_kernel(TrArgs a){
  int bx = blockIdx.x;
  int mi = 0;
  #pragma unroll
  for (int i = 0; i < 8; ++i) if (bx >= a.start[i+1]) mi = i+1;
  int t = bx - a.start[mi];
  int K = a.K[mi], N = a.N[mi];
  int ntk = K >> 5;
  int tk = t % ntk, tn = t / ntk;
  int k0 = tk*32, n0 = tn*32;
  __shared__ u16 lds[32][33];
  int c = threadIdx.x & 31, r = threadIdx.x >> 5;
  const float* src = a.src[mi];
  u16* dst = a.dst[mi];
  #pragma unroll
  for (int ii = 0; ii < 4; ++ii){
    int row = r + ii*8;
    lds[row][c] = f2b(src[(size_t)(k0+row)*N + n0 + c]);
  }
  __syncthreads();
  #pragma unroll
  for (int ii = 0; ii < 4; ++ii){
    int row = r + ii*8;
    dst[(size_t)(n0+row)*K + k0 + c] = lds[c][row];
  }
}

// ---------------- adaLN: s = silu(global_c); mod = s @ ada_w + ada_b (fp32 out) ----------------
__global__ __launch_bounds__(256) void ada_kernel(const float* gc, const float* wx, const float* bx,
                                                  const float* wc, const float* bc,
                                                  float* mod_x, float* mod_c){
  __shared__ float s[4][C_];
  __shared__ float part[4][4][64];
  int tid = threadIdx.x;
  for (int i = tid; i < 4*C_; i += 256){
    float v = gc[i];
    s[i / C_][i % C_] = v / (1.f + __expf(-v));
  }
  __syncthreads();
  int jq = tid & 63;
  int kq = tid >> 6;
  int jg = blockIdx.x*64 + jq;
  int which = jg / 6912;
  int j = jg % 6912;
  const float* W = which ? wc : wx;
  float a0=0.f, a1=0.f, a2=0.f, a3=0.f;
  for (int k = kq*288; k < kq*288 + 288; ++k){
    float w = W[(size_t)k*6912 + j];
    a0 += s[0][k]*w; a1 += s[1][k]*w; a2 += s[2][k]*w; a3 += s[3][k]*w;
  }
  part[kq][0][jq]=a0; part[kq][1][jq]=a1; part[kq][2][jq]=a2; part[kq][3][jq]=a3;
  __syncthreads();
  if (kq == 0){
    float bb = (which ? bc : bx)[j];
    float* out = which ? mod_c : mod_x;
    #pragma unroll
    for (int b = 0; b < 4; ++b){
      out[(size_t)b*6912 + j] = part[0][b][jq] + part[1][b][jq] + part[2][b][jq] + part[3][b][jq] + bb;
    }
  }
}

// ---------------- fused LayerNorm + modulate (fp32 in, bf16 out) ----------------
__global__ __launch_bounds__(256) void ln_mod_kernel(
  const float* srcx, const float* srcc, const float* g, const float* bt,
  const float* gcn, const float* btc,
  const float* shx, const float* scx, const float* shc, const float* scc,
  u16* out)
{
  int m = blockIdx.x;
  bool isC = (m >= MX_);
  const float* src = isC ? srcc + (size_t)(m - MX_)*C_ : srcx + (size_t)m*C_;
  int bidx = isC ? ((m - MX_) >> 7) : (m >> 10);
  const float* gg = isC ? gcn : g;
  const float* bb = isC ? btc : bt;
  const float* sh = (isC ? shc : shx) + (size_t)bidx*6912;
  const float* sc = (isC ? scc : scx) + (size_t)bidx*6912;
  int tid = threadIdx.x;
  float lv[8];
  float sum = 0.f, sq = 0.f;
  if (tid < 144){
    float4 v0 = *(const float4*)(src + tid*8);
    float4 v1 = *(const float4*)(src + tid*8 + 4);
    lv[0]=v0.x; lv[1]=v0.y; lv[2]=v0.z; lv[3]=v0.w;
    lv[4]=v1.x; lv[5]=v1.y; lv[6]=v1.z; lv[7]=v1.w;
    #pragma unroll
    for (int j = 0; j < 8; ++j){ sum += lv[j]; sq += lv[j]*lv[j]; }
  }
  #pragma unroll
  for (int off = 1; off < 64; off <<= 1){ sum += __shfl_xor(sum, off); sq += __shfl_xor(sq, off); }
  __shared__ float rs[4], rq[4];
  int wave = tid >> 6, lane = tid & 63;
  if (lane == 0){ rs[wave] = sum; rq[wave] = sq; }
  __syncthreads();
  float S = rs[0]+rs[1]+rs[2]+rs[3];
  float Q = rq[0]+rq[1]+rq[2]+rq[3];
  float mean = S * (1.f/1152.f);
  float var  = Q * (1.f/1152.f) - mean*mean;
  float rstd = rsqrtf(var + 1e-6f);
  if (tid < 144){
    union { uint4 v; u16 s[8]; } o;
    #pragma unroll
    for (int j = 0; j < 8; ++j){
      int n = tid*8 + j;
      float val = (lv[j] - mean)*rstd*gg[n] + bb[n];
      val = val*(1.f + sc[n]) + sh[n];
      o.s[j] = f2b(val);
    }
    *(uint4*)(out + (size_t)m*C_ + tid*8) = o.v;
  }
}

// ---------------- GEMM: C = A @ B(^T stored) + bias, with epilogues ----------------
// EPI 0: bias; EPI 1: gelu(bias+acc); EPI 2: resid + gate*(acc+bias)
struct GemmArgs {
  const u16* A; int lda; int rowmap;       // rowmap 1 = O-buffer token map
  const u16* BTx; const u16* BTc;          // [N][K] bf16 row-major (pre-transposed)
  const float* biasx; const float* biasc;
  void* outx; void* outc;                  // bf16 (OF32=0) or fp32 (OF32=1)
  const float* residx; const float* residc;
  const float* gatex; const float* gatec;  // + b*6912 applied inside
  int N, K;
};

static __device__ __forceinline__ int amap(int m, int rowmap){
  if (rowmap){
    if (m < MX_) return (m >> 10)*NT_ + (m & 1023);
    int mm = m - MX_;
    return (mm >> 7)*NT_ + 1024 + (mm & 127);
  }
  return m;
}

template<int EPI, int OF32>
__global__ __launch_bounds__(256, 2) void gemm_kernel(GemmArgs g){
  __shared__ u16 As[128*64];
  __shared__ u16 Bs[128*64];
  int n0 = blockIdx.x*128, m0 = blockIdx.y*128;
  bool isC = (m0 >= MX_);
  const u16* BT = isC ? g.BTc : g.BTx;
  int tid = threadIdx.x, wave = tid >> 6, lane = tid & 63;
  int lg = lane >> 4, lr = lane & 15;
  int wm = wave >> 1, wn = wave & 1;
  f32x4 acc[4][4] = {};
  for (int k0 = 0; k0 < g.K; k0 += 64){
    #pragma unroll
    for (int i = 0; i < 4; ++i){
      int cb = (wave*4 + i)*64;
      int q = cb + lane;
      int row = q >> 3;
      int c16 = (q & 7) ^ (row & 7);            // XOR-swizzle: both-sides (stage source pre-swizzled)
      gl_lds16(g.A + (size_t)amap(m0 + row, g.rowmap)*g.lda + k0 + c16*8, As + cb*8);
      gl_lds16(BT + (size_t)(n0 + row)*g.K + k0 + c16*8, Bs + cb*8);
    }
    __syncthreads();
    #pragma unroll
    for (int kkI = 0; kkI < 2; ++kkI){
      bf16x8 af[4], bfr[4];
      #pragma unroll
      for (int mi = 0; mi < 4; ++mi){
        int row = wm*64 + mi*16 + lr;
        int c16 = (kkI*4 + lg) ^ (row & 7);
        af[mi] = *(const bf16x8*)&As[row*64 + c16*8];
      }
      #pragma unroll
      for (int ni = 0; ni < 4; ++ni){
        int row = wn*64 + ni*16 + lr;
        int c16 = (kkI*4 + lg) ^ (row & 7);
        bfr[ni] = *(const bf16x8*)&Bs[row*64 + c16*8];
      }
      #pragma unroll
      for (int mi = 0; mi < 4; ++mi)
        #pragma unroll
        for (int ni = 0; ni < 4; ++ni)
          acc[mi][ni] = __builtin_amdgcn_mfma_f32_16x16x32_bf16(af[mi], bfr[ni], acc[mi][ni], 0, 0, 0);
    }
    __syncthreads();
  }
  // epilogue
  const float* bias  = isC ? g.biasc : g.biasx;
  const float* resid = isC ? g.residc : g.residx;
  void* out = isC ? g.outc : g.outx;
  const float* gate = nullptr;
  if (EPI == 2){
    int bidx = isC ? ((m0 - MX_) >> 7) : (m0 >> 10);
    gate = (isC ? g.gatec : g.gatex) + (size_t)bidx*6912;
  }
  int mbase = isC ? (m0 - MX_) : m0;
  #pragma unroll
  for (int mi = 0; mi < 4; ++mi){
    #pragma unroll
    for (int r = 0; r < 4; ++r){
      size_t orow = (size_t)(mbase + wm*64 + mi*16 + lg*4 + r);
      #pragma unroll
      for (int ni = 0; ni < 4; ++ni){
        int n = n0 + wn*64 + ni*16 + lr;
        float v = acc[mi][ni][r] + bias[n];
        if (EPI == 1){
          float u = 0.7978845608028654f*(v + 0.044715f*v*v*v);
          v = 0.5f*v*(1.f + tanhf(u));
        }
        if (EPI == 2){
          v = resid[orow*(size_t)g.N + n] + gate[n]*v;
        }
        if (OF32) ((float*)out)[orow*(size_t)g.N + n] = v;
        else      ((u16*)out)[orow*(size_t)g.N + n] = f2b(v);
      }
    }
  }
}

// ---------------- head split + RMS-norm(q,k) + zero-pad to 96 + V transpose ----------------
__global__ __launch_bounds__(256) void rmshead_kernel(
  const u16* qkv, const float* gqx, const float* gkx, const float* gqc, const float* gkc,
  u16* qpad, u16* kpad, u16* vT)
{
  int tt = blockIdx.x, h = blockIdx.y, b = blockIdx.z;
  int t0 = tt*64;
  bool isC = (t0 >= 1024);
  size_t rowbase = isC ? (size_t)(MX_ + b*128 + (t0 - 1024)) : (size_t)(b*1024 + t0);
  __shared__ u16 sq[2][64][72];
  __shared__ u16 sv[64][72];
  __shared__ float nf[2][64];
  int tid = threadIdx.x;
  for (int s = tid; s < 1728; s += 256){
    int which = s / 576, rem = s % 576;
    int t = rem / 9, ch = rem % 9;
    uint4 v = *(const uint4*)(qkv + (rowbase + t)*3456 + which*C_ + h*D_ + ch*8);
    u16* dst = (which < 2) ? &sq[which][t][ch*8] : &sv[t][ch*8];
    *(uint4*)dst = v;
  }
  __syncthreads();
  {
    int row = tid >> 1, half = tid & 1;
    int which = row >> 6, t = row & 63;
    float ss = 0.f;
    for (int d = half*36; d < half*36 + 36; ++d){
      float v = b2f(sq[which][t][d]); ss += v*v;
    }
    ss += __shfl_xor(ss, 1);
    if (half == 0){
      const float* gp = (which == 0) ? (isC ? gqc : gqx) : (isC ? gkc : gkx);
      nf[which][t] = 33.9411254970f * gp[0] / fmaxf(sqrtf(ss), 1e-12f);
    }
  }
  __syncthreads();
  size_t obase = ((size_t)(b*H_ + h)*NT_ + t0) * DP_;
  for (int s = tid; s < 1536; s += 256){
    int which = s / 768, rem = s % 768;
    int t = rem / 12, ch = rem % 12;
    float f = nf[which][t];
    union { uint4 v; u16 e[8]; } o;
    #pragma unroll
    for (int j = 0; j < 8; ++j){
      int d = ch*8 + j;
      o.e[j] = (d < D_) ? f2b(b2f(sq[which][t][d]) * f) : (u16)0;
    }
    *(uint4*)((which == 0 ? qpad : kpad) + obase + (size_t)t*DP_ + ch*8) = o.v;
  }
  size_t vbase = (size_t)(b*H_ + h)*80*NT_;
  for (int s = tid; s < 576; s += 256){
    int d = s / 8, ch = s % 8;
    union { uint4 v; u16 e[8]; } o;
    #pragma unroll
    for (int j = 0; j < 8; ++j) o.e[j] = sv[ch*8 + j][d];
    *(uint4*)(vT + vbase + (size_t)d*NT_ + t0 + ch*8) = o.v;
  }
}

// ---------------- flash attention: per (qtile, h, b) ----------------
__global__ __launch_bounds__(256, 2) void attn_kernel(
  const u16* qpad, const u16* kpad, const u16* vT, u16* O)
{
  int qt = blockIdx.x, h = blockIdx.y, b = blockIdx.z;
  int bh = b*H_ + h;
  __shared__ u16 Qs[64][104];
  __shared__ u16 Ks[64][104];
  __shared__ u16 Vs[80][72];
  __shared__ u16 Ps[64][72];
  __shared__ float fl[64];
  __shared__ float ll[64];
  int tid = threadIdx.x, wave = tid >> 6, lane = tid & 63;
  int lg = lane >> 4, lr = lane & 15;
  const u16* qbase = qpad + ((size_t)bh*NT_ + qt*64)*DP_;
  for (int i = wave; i < 13; i += 4){
    int slot = i*64 + lane;
    int row = slot / 13, ch = slot % 13;
    gl_lds16(qbase + (size_t)row*DP_ + ch*8, &Qs[0][0] + i*512);
  }
  f32x4 acc[5] = {};
  float m_r[4], l_r[4];
  #pragma unroll
  for (int r = 0; r < 4; ++r){ m_r[r] = -1e30f; l_r[r] = 0.f; }
  const u16* kbase0 = kpad + (size_t)bh*NT_*DP_;
  const u16* vbase0 = vT + (size_t)bh*80*NT_;
  for (int kvt = 0; kvt < 18; ++kvt){
    const u16* kb = kbase0 + (size_t)kvt*64*DP_;
    for (int i = wave; i < 13; i += 4){
      int slot = i*64 + lane;
      int row = slot / 13, ch = slot % 13;
      gl_lds16(kb + (size_t)row*DP_ + ch*8, &Ks[0][0] + i*512);
    }
    const u16* vb = vbase0 + kvt*64;
    for (int i = wave; i < 12; i += 4){
      int slot = i*64 + lane;
      if (slot < 720){
        int row = slot / 9, ch = slot % 9;
        gl_lds16(vb + (size_t)row*NT_ + ch*8, &Vs[0][0] + i*512);
      }
    }
    __syncthreads();
    // S = Q K^T (K-dim 96)
    f32x4 s[4] = {};
    bf16x8 aq[3];
    int qrow = wave*16 + lr;
    #pragma unroll
    for (int kkI = 0; kkI < 3; ++kkI) aq[kkI] = *(const bf16x8*)&Qs[qrow][(kkI*4 + lg)*8];
    #pragma unroll
    for (int nb = 0; nb < 4; ++nb){
      int krow = nb*16 + lr;
      #pragma unroll
      for (int kkI = 0; kkI < 3; ++kkI){
        bf16x8 bk = *(const bf16x8*)&Ks[krow][(kkI*4 + lg)*8];
        s[nb] = __builtin_amdgcn_mfma_f32_16x16x32_bf16(aq[kkI], bk, s[nb], 0, 0, 0);
      }
    }
    // online softmax; lane holds rows (16w + lg*4 + r), cols (nb*16 + lr)
    float p[4][4];
    #pragma unroll
    for (int nb = 0; nb < 4; ++nb)
      #pragma unroll
      for (int r = 0; r < 4; ++r) p[nb][r] = s[nb][r] * 0.11785113019775793f;
    float fac[4];
    #pragma unroll
    for (int r = 0; r < 4; ++r){
      float mx = fmaxf(fmaxf(p[0][r], p[1][r]), fmaxf(p[2][r], p[3][r]));
      #pragma unroll
      for (int off = 1; off < 16; off <<= 1) mx = fmaxf(mx, __shfl_xor(mx, off));
      float mn = fmaxf(m_r[r], mx);
      fac[r] = __expf(m_r[r] - mn);
      m_r[r] = mn;
      float rsum = 0.f;
      #pragma unroll
      for (int nb = 0; nb < 4; ++nb){ p[nb][r] = __expf(p[nb][r] - mn); rsum += p[nb][r]; }
      #pragma unroll
      for (int off = 1; off < 16; off <<= 1) rsum += __shfl_xor(rsum, off);
      l_r[r] = l_r[r]*fac[r] + rsum;
    }
    #pragma unroll
    for (int nb = 0; nb < 4; ++nb)
      #pragma unroll
      for (int r = 0; r < 4; ++r)
        Ps[wave*16 + lg*4 + r][nb*16 + lr] = f2b(p[nb][r]);
    if (lr == 0){
      #pragma unroll
      for (int r = 0; r < 4; ++r) fl[wave*16 + lg*4 + r] = fac[r];
    }
    __syncthreads();
    // O^T = V^T P^T ; rescale acc first (per q-col factor)
    float fc = fl[wave*16 + lr];
    #pragma unroll
    for (int dc = 0; dc < 5; ++dc)
      #pragma unroll
      for (int j = 0; j < 4; ++j) acc[dc][j] *= fc;
    #pragma unroll
    for (int kkI = 0; kkI < 2; ++kkI){
      bf16x8 bp = *(const bf16x8*)&Ps[wave*16 + lr][(kkI*4 + lg)*8];
      #pragma unroll
      for (int dc = 0; dc < 5; ++dc){
        bf16x8 av = *(const bf16x8*)&Vs[dc*16 + lr][(kkI*4 + lg)*8];
        acc[dc] = __builtin_amdgcn_mfma_f32_16x16x32_bf16(av, bp, acc[dc], 0, 0, 0);
      }
    }
    __syncthreads();
  }
  if (lr == 0){
    #pragma unroll
    for (int r = 0; r < 4; ++r) ll[wave*16 + lg*4 + r] = l_r[r];
  }
  __syncthreads();
  float rl = 1.f / ll[wave*16 + lr];
  size_t orow = (size_t)b*NT_ + qt*64 + wave*16 + lr;
  #pragma unroll
  for (int dc = 0; dc < 5; ++dc){
    int d0 = dc*16 + lg*4;
    if (d0 < D_){
      union { uint2 v; u16 e[4]; } o;
      #pragma unroll
      for (int r = 0; r < 4; ++r) o.e[r] = f2b(acc[dc][r] * rl);
      *(uint2*)(O + orow*C_ + h*D_ + d0) = o.v;
    }
  }
}

// ---------------- host ----------------
extern "C" void kernel_launch(void* const* d_in, const int* in_sizes, int n_in,
                              void* d_out, int out_size, void* d_ws, size_t ws_size,
                              hipStream_t stream)
{
  (void)in_sizes; (void)n_in; (void)out_size; (void)ws_size;
  const float* x        = (const float*)d_in[0];
  const float* c        = (const float*)d_in[1];
  const float* gc       = (const float*)d_in[2];
  const float* ada_x_w  = (const float*)d_in[3];
  const float* ada_x_b  = (const float*)d_in[4];
  const float* ada_c_w  = (const float*)d_in[5];
  const float* ada_c_b  = (const float*)d_in[6];
  const float* g1x_g    = (const float*)d_in[7];
  const float* g1x_b    = (const float*)d_in[8];
  const float* g2x_g    = (const float*)d_in[9];
  const float* g2x_b    = (const float*)d_in[10];
  const float* g1c_g    = (const float*)d_in[11];
  const float* g1c_b    = (const float*)d_in[12];
  const float* g2c_g    = (const float*)d_in[13];
  const float* g2c_b    = (const float*)d_in[14];
  const float* qkv_x_w  = (const float*)d_in[15];
  const float* qkv_x_b  = (const float*)d_in[16];
  const float* proj_x_w = (const float*)d_in[17];
  const float* proj_x_b = (const float*)d_in[18];
  const float* qkv_c_w  = (const float*)d_in[19];
  const float* qkv_c_b  = (const float*)d_in[20];
  const float* proj_c_w = (const float*)d_in[21];
  const float* proj_c_b = (const float*)d_in[22];
  const float* gq_x     = (const float*)d_in[23];
  const float* gk_x     = (const float*)d_in[24];
  const float* gq_c     = (const float*)d_in[25];
  const float* gk_c     = (const float*)d_in[26];
  const float* m_x_w1   = (const float*)d_in[27];
  const float* m_x_b1   = (const float*)d_in[28];
  const float* m_x_w2   = (const float*)d_in[29];
  const float* m_x_b2   = (const float*)d_in[30];
  const float* m_c_w1   = (const float*)d_in[31];
  const float* m_c_b1   = (const float*)d_in[32];
  const float* m_c_w2   = (const float*)d_in[33];
  const float* m_c_b2   = (const float*)d_in[34];
  float* out = (float*)d_out;

  char* ws = (char*)d_ws;
  size_t off = 0;
  auto alloc = [&](size_t bytes)->void*{ void* p = ws + off; off += (bytes + 255) & ~(size_t)255; return p; };
  u16* WTqx  = (u16*)alloc((size_t)3456*1152*2);
  u16* WTqc  = (u16*)alloc((size_t)3456*1152*2);
  u16* WTpx  = (u16*)alloc((size_t)1152*1152*2);
  u16* WTpc  = (u16*)alloc((size_t)1152*1152*2);
  u16* WTm1x = (u16*)alloc((size_t)4608*1152*2);
  u16* WTm2x = (u16*)alloc((size_t)1152*4608*2);
  u16* WTm1c = (u16*)alloc((size_t)4608*1152*2);
  u16* WTm2c = (u16*)alloc((size_t)1152*4608*2);
  float* mod_x = (float*)alloc((size_t)4*6912*4);
  float* mod_c = (float*)alloc((size_t)4*6912*4);
  u16* xin  = (u16*)alloc((size_t)4608*1152*2);
  u16* pool = (u16*)alloc((size_t)4608*4608*2);     // qkv out, later MLP hidden
  u16* qpad = (u16*)alloc((size_t)64*1152*96*2 + 4096);
  u16* kpad = (u16*)alloc((size_t)64*1152*96*2 + 4096);
  u16* vTb  = (u16*)alloc((size_t)64*80*1152*2 + 4096);
  u16* Obuf = (u16*)alloc((size_t)4*1152*1152*2);
  float* x1c1 = (float*)alloc((size_t)4608*1152*4);

  // L0: weight transposes (fp32 -> bf16 [N][K])
  {
    TrArgs ta;
    const float* srcs[8] = {qkv_x_w, qkv_c_w, proj_x_w, proj_c_w, m_x_w1, m_x_w2, m_c_w1, m_c_w2};
    u16* dsts[8]         = {WTqx, WTqc, WTpx, WTpc, WTm1x, WTm2x, WTm1c, WTm2c};
    int Ks[8] = {1152,1152,1152,1152,1152,4608,1152,4608};
    int Ns[8] = {3456,3456,1152,1152,4608,1152,4608,1152};
    int st = 0;
    for (int i = 0; i < 8; ++i){
      ta.src[i] = srcs[i]; ta.dst[i] = dsts[i]; ta.K[i] = Ks[i]; ta.N[i] = Ns[i];
      ta.start[i] = st; st += (Ks[i]/32)*(Ns[i]/32);
    }
    ta.start[8] = st;
    transpose_kernel<<<dim3(st), dim3(256), 0, stream>>>(ta);
  }
  // L1: adaLN modulation vectors
  ada_kernel<<<dim3(216), dim3(256), 0, stream>>>(gc, ada_x_w, ada_x_b, ada_c_w, ada_c_b, mod_x, mod_c);
  // L2: LN1 + modulate
  ln_mod_kernel<<<dim3(4608), dim3(256), 0, stream>>>(
      x, c, g1x_g, g1x_b, g1c_g, g1c_b,
      mod_x + 0, mod_x + 1152, mod_c + 0, mod_c + 1152, xin);
  // L3: qkv GEMM (merged x|c)
  {
    GemmArgs ga{};
    ga.A = xin; ga.lda = 1152; ga.rowmap = 0;
    ga.BTx = WTqx; ga.BTc = WTqc; ga.biasx = qkv_x_b; ga.biasc = qkv_c_b;
    ga.outx = pool; ga.outc = pool + (size_t)4096*3456;
    ga.N = 3456; ga.K = 1152;
    gemm_kernel<0,0><<<dim3(27,36), dim3(256), 0, stream>>>(ga);
  }
  // L4: head split + RMS + pad + V^T
  rmshead_kernel<<<dim3(18,16,4), dim3(256), 0, stream>>>(pool, gq_x, gk_x, gq_c, gk_c, qpad, kpad, vTb);
  // L5: attention
  attn_kernel<<<dim3(18,16,4), dim3(256), 0, stream>>>(qpad, kpad, vTb, Obuf);
  // L6: proj + gated residual -> x1c1 (fp32)
  {
    GemmArgs ga{};
    ga.A = Obuf; ga.lda = 1152; ga.rowmap = 1;
    ga.BTx = WTpx; ga.BTc = WTpc; ga.biasx = proj_x_b; ga.biasc = proj_c_b;
    ga.outx = x1c1; ga.outc = x1c1 + (size_t)4096*1152;
    ga.residx = x; ga.residc = c;
    ga.gatex = mod_x + 2*1152; ga.gatec = mod_c + 2*1152;
    ga.N = 1152; ga.K = 1152;
    gemm_kernel<2,1><<<dim3(9,36), dim3(256), 0, stream>>>(ga);
  }
  // L7: LN2 + modulate (reads fp32 x1c1)
  ln_mod_kernel<<<dim3(4608), dim3(256), 0, stream>>>(
      x1c1, x1c1 + (size_t)4096*1152, g2x_g, g2x_b, g2c_g, g2c_b,
      mod_x + 3*1152, mod_x + 4*1152, mod_c + 3*1152, mod_c + 4*1152, xin);
  // L8: MLP fc1 + GELU
  {
    GemmArgs ga{};
    ga.A = xin; ga.lda = 1152; ga.rowmap = 0;
    ga.BTx = WTm1x; ga.BTc = WTm1c; ga.biasx = m_x_b1; ga.biasc = m_c_b1;
    ga.outx = pool; ga.outc = pool + (size_t)4096*4608;
    ga.N = 4608; ga.K = 1152;
    gemm_kernel<1,0><<<dim3(36,36), dim3(256), 0, stream>>>(ga);
  }
  // L9: MLP fc2 + gated residual -> d_out (fp32)
  {
    GemmArgs ga{};
    ga.A = pool; ga.lda = 4608; ga.rowmap = 0;
    ga.BTx = WTm2x; ga.BTc = WTm2c; ga.biasx = m_x_b2; ga.biasc = m_c_b2;
    ga.outx = out; ga.outc = out + (size_t)4096*1152;
    ga.residx = x1c1; ga.residc = x1c1 + (size_t)4096*1152;
    ga.gatex = mod_x + 5*1152; ga.gatec = mod_c + 5*1152;
    ga.N = 1152; ga.K = 4608;
    gemm_kernel<2,1><<<dim3(9,36), dim3(256), 0, stream>>>(ga);
  }
}